// Round 1
// 1848.443 us; speedup vs baseline: 1.0978x; 1.0978x over previous
//
#include <hip/hip_runtime.h>

#define T_STEPS 512
#define D_IN    64
#define BC      4      // batch columns per block
#define NW      64     // max per-thread weight floats
#define BLOCK   512

// ---------------------------------------------------------------------------
// Layer-skewed pipeline: at tick tau, layer l computes timestep t = tau - l,
// out-proj computes t = tau - 5. All sections within a tick are independent
// (read states written last tick) -> 2 barriers per tick instead of 11.
//
// R(this): BC=2 ran 512 blocks but OccupancyPercent=23.7% ~= 8/32 waves/CU
// showed only ONE 8-wave block resident per CU -> the grid ran as TWO
// sequential ~960us rounds. Tick is latency-bound (VALUBusy 27%), so BC=4
// doubles per-thread work nearly for free and halves the grid to 256 blocks
// = 1 block/CU = ONE round.
//
// __launch_bounds__(512, 1): VGPR cap 256. We need only 8 waves/CU (one
// block); capping at 128 (the old (512,2)) risks spilling the enlarged
// accumulator/prefetch state -> 3.7 GB HBM scratch traffic (R2 post-mortem).
//
// Section table (G phase, all concurrent, disjoint tid ranges):
//   sec  role  G   K  klen kc  thr  tid-range  gbase  input
//   s0   ih0   96  64  16   4   96    0-95       0    inv (x)
//   s1   hh0   96  32   8   4   96   96-191     96    hbuf[0]
//   s9   hh4   96  32  16   2   48  192-239    528    hbuf[4]
//   s2   ih1   48  32   8   4   48  240-287    192    hbuf[0]
//   s3   hh1   48  16   8   2   24  288-311    240    hbuf[1]
//   s7   hh3   48  16   8   2   24  312-335    384    hbuf[3]
//   s8   ih4   96  16   8   2   48  336-383    432    hbuf[3]
//   s10  out   64  32   8   4   64  384-447     --    hbuf[4] -> global
//   s4   ih2   24  16   8   2   12  448-459    288    hbuf[1]
//   s5   hh2   24   8   8   1    6  460-465    312    hbuf[2]
//   s6   ih3   48   8   8   1   12  466-477    336    hbuf[2]
//   x-prefetch: tid 480-511 (32 thr x 2 float4 = 256 floats = x tile, BC=4)
// Section starts are multiples of KC (butterfly groups never straddle waves).
// Gate rows: gi0:0 gh0:96 gi1:192 gh1:240 gi2:288 gh2:312 gi3:336 gh3:384
//            gi4:432 gh4:528  (624 rows x BC floats)
//
// ROT: with BC=4 the inv reads are float4 (16B) -> bank slot = ke mod 8.
// KC=4 sections with stride-8/16 k0 alias all kci onto the same slot, so
// ROT=2 rotates the k-walk per kci: slots {kk,kk+2,kk+4,kk+6} distinct mod 8.
// Applied to every KC>=2 section (weights are stored pre-rotated to match).
// ---------------------------------------------------------------------------

__device__ __forceinline__ float sigmoid_f(float x) {
    return 1.0f / (1.0f + __expf(-x));
}
__device__ __forceinline__ float tanh_f(float x) {
    return 1.0f - 2.0f / (__expf(2.0f * x) + 1.0f);
}

template<int KLEN, int KC, int ROT>
__device__ __forceinline__ void load_sec(float (&wr)[NW], float (&bs)[4], int local,
                                         const float* __restrict__ W,
                                         const float* __restrict__ bv, int K)
{
    const int gb = local / KC, kci = local % KC;
    const int g0 = gb * 4, k0 = kci * KLEN;
    const int start = (ROT * kci) & (KLEN - 1);
#pragma unroll
    for (int j = 0; j < 4; ++j) {
#pragma unroll
        for (int kk = 0; kk < KLEN; ++kk) {
            const int ke = k0 + ((kk + start) & (KLEN - 1));
            wr[j * KLEN + kk] = W[(g0 + j) * K + ke];
        }
        bs[j] = bv[g0 + j];
    }
}

template<int KLEN, int KC, int ROT>
__device__ __forceinline__ void gemm_sec(const float (&wr)[NW], const float (&bs)[4],
                                         int local, const float* __restrict__ inv,
                                         float* __restrict__ gate, int gbase)
{
    const int gb = local / KC, kci = local % KC;
    const int g0 = gb * 4, k0 = kci * KLEN;
    const int start = (ROT * kci) & (KLEN - 1);
    float acc[4][BC];
#pragma unroll
    for (int j = 0; j < 4; ++j) {
        const float bj = (kci == 0) ? bs[j] : 0.0f;
#pragma unroll
        for (int b = 0; b < BC; ++b) acc[j][b] = bj;
    }
#pragma unroll
    for (int kk = 0; kk < KLEN; ++kk) {
        const int ke = k0 + ((kk + start) & (KLEN - 1));
        const float4 v = *(const float4*)&inv[ke * BC];
#pragma unroll
        for (int j = 0; j < 4; ++j) {
            const float w = wr[j * KLEN + kk];
            acc[j][0] = fmaf(w, v.x, acc[j][0]);
            acc[j][1] = fmaf(w, v.y, acc[j][1]);
            acc[j][2] = fmaf(w, v.z, acc[j][2]);
            acc[j][3] = fmaf(w, v.w, acc[j][3]);
        }
    }
#pragma unroll
    for (int m = 1; m < KC; m <<= 1)
#pragma unroll
        for (int j = 0; j < 4; ++j) {
#pragma unroll
            for (int b = 0; b < BC; ++b)
                acc[j][b] += __shfl_xor(acc[j][b], m, 64);
        }
    if (kci == 0) {
#pragma unroll
        for (int j = 0; j < 4; ++j) {
            float4 o = {acc[j][0], acc[j][1], acc[j][2], acc[j][3]};
            *(float4*)&gate[(gbase + g0 + j) * BC] = o;
        }
    }
}

template<int KLEN, int KC, int ROT>
__device__ __forceinline__ void out_sec(const float (&wr)[NW], const float (&bs)[4],
                                        int local, const float* __restrict__ inv,
                                        float* __restrict__ outp /* = out + (b0*T + t)*64 */)
{
    const int gb = local / KC, kci = local % KC;
    const int g0 = gb * 4, k0 = kci * KLEN;
    const int start = (ROT * kci) & (KLEN - 1);
    float acc[4][BC];
#pragma unroll
    for (int j = 0; j < 4; ++j) {
        const float bj = (kci == 0) ? bs[j] : 0.0f;
#pragma unroll
        for (int b = 0; b < BC; ++b) acc[j][b] = bj;
    }
#pragma unroll
    for (int kk = 0; kk < KLEN; ++kk) {
        const int ke = k0 + ((kk + start) & (KLEN - 1));
        const float4 v = *(const float4*)&inv[ke * BC];
#pragma unroll
        for (int j = 0; j < 4; ++j) {
            const float w = wr[j * KLEN + kk];
            acc[j][0] = fmaf(w, v.x, acc[j][0]);
            acc[j][1] = fmaf(w, v.y, acc[j][1]);
            acc[j][2] = fmaf(w, v.z, acc[j][2]);
            acc[j][3] = fmaf(w, v.w, acc[j][3]);
        }
    }
#pragma unroll
    for (int m = 1; m < KC; m <<= 1)
#pragma unroll
        for (int j = 0; j < 4; ++j) {
#pragma unroll
            for (int b = 0; b < BC; ++b)
                acc[j][b] += __shfl_xor(acc[j][b], m, 64);
        }
    if (kci == 0) {
#pragma unroll
        for (int b = 0; b < BC; ++b) {
            float4 o = {acc[0][b], acc[1][b], acc[2][b], acc[3][b]};
            *(float4*)&outp[(size_t)b * (T_STEPS * 64) + g0] = o;
        }
    }
}

__device__ __forceinline__ void upd(int H, float* __restrict__ hrow, int local,
                                    const float* __restrict__ gate, int ihb, int hhb)
{
    const int h = local >> 2, b = local & 3;
    const float ir  = gate[(ihb + h) * BC + b];
    const float hr  = gate[(hhb + h) * BC + b];
    const float iz  = gate[(ihb + H + h) * BC + b];
    const float hz  = gate[(hhb + H + h) * BC + b];
    const float in_ = gate[(ihb + 2 * H + h) * BC + b];
    const float hn  = gate[(hhb + 2 * H + h) * BC + b];
    const float r = sigmoid_f(ir + hr);
    const float z = sigmoid_f(iz + hz);
    const float n = tanh_f(in_ + r * hn);
    hrow[h * BC + b] = (1.0f - z) * n + z * hrow[h * BC + b];
}

__global__ __launch_bounds__(BLOCK, 1)
void gru_kernel(const float* __restrict__ X,
                const float* wih0, const float* whh0, const float* bih0, const float* bhh0,
                const float* wih1, const float* whh1, const float* bih1, const float* bhh1,
                const float* wih2, const float* whh2, const float* bih2, const float* bhh2,
                const float* wih3, const float* whh3, const float* bih3, const float* bhh3,
                const float* wih4, const float* whh4, const float* bih4, const float* bhh4,
                const float* wout, const float* bout,
                float* __restrict__ out)
{
    __shared__ __align__(16) float inv0[D_IN * BC];    // x(tau) tile [d][b]
    __shared__ __align__(16) float hbuf[5][32 * BC];   // h states [l][h][b]
    __shared__ __align__(16) float gate[624 * BC];     // gate partials [row][b]

    const int tid = threadIdx.x;
    const int b0  = blockIdx.x * BC;

    float wr[NW];
    float bs[4];

    // ---- startup: per-thread weight slices into registers (one section each) ----
    if      (tid < 96)  load_sec<16, 4, 2>(wr, bs, tid,       wih0, bih0, 64);  // s0
    else if (tid < 192) load_sec< 8, 4, 2>(wr, bs, tid - 96,  whh0, bhh0, 32);  // s1
    else if (tid < 240) load_sec<16, 2, 2>(wr, bs, tid - 192, whh4, bhh4, 32);  // s9
    else if (tid < 288) load_sec< 8, 4, 2>(wr, bs, tid - 240, wih1, bih1, 32);  // s2
    else if (tid < 312) load_sec< 8, 2, 2>(wr, bs, tid - 288, whh1, bhh1, 16);  // s3
    else if (tid < 336) load_sec< 8, 2, 2>(wr, bs, tid - 312, whh3, bhh3, 16);  // s7
    else if (tid < 384) load_sec< 8, 2, 2>(wr, bs, tid - 336, wih4, bih4, 16);  // s8
    else if (tid < 448) load_sec< 8, 4, 2>(wr, bs, tid - 384, wout, bout, 32);  // s10
    else if (tid < 460) load_sec< 8, 2, 2>(wr, bs, tid - 448, wih2, bih2, 16);  // s4
    else if (tid < 466) load_sec< 8, 1, 0>(wr, bs, tid - 460, whh2, bhh2, 8);   // s5
    else if (tid < 478) load_sec< 8, 1, 0>(wr, bs, tid - 466, wih3, bih3, 8);   // s6

    // ---- zero states, stage x(0) ----
    for (int i = tid; i < 5 * 32 * BC; i += BLOCK) ((float*)hbuf)[i] = 0.0f;
    if (tid >= 480) {
        const int e = tid - 480, b = e >> 4, d0 = (e & 15) << 2;
#pragma unroll
        for (int bb = 0; bb < 2; ++bb) {
            const int bi = b + 2 * bb;
            const float4 v = *(const float4*)&X[(size_t)(b0 + bi) * (T_STEPS * D_IN) + d0];
            inv0[(d0 + 0) * BC + bi] = v.x; inv0[(d0 + 1) * BC + bi] = v.y;
            inv0[(d0 + 2) * BC + bi] = v.z; inv0[(d0 + 3) * BC + bi] = v.w;
        }
    }
    __syncthreads();

    float4 xr0 = {0.f, 0.f, 0.f, 0.f};
    float4 xr1 = {0.f, 0.f, 0.f, 0.f};

    for (int tau = 0; tau < T_STEPS + 5; ++tau) {
        // ================= G phase: all gemms concurrent =================
        if (tid < 96) {
            if (tau < 512)              gemm_sec<16, 4, 2>(wr, bs, tid,       inv0,    gate, 0);
        } else if (tid < 192) {
            if (tau < 512)              gemm_sec< 8, 4, 2>(wr, bs, tid - 96,  hbuf[0], gate, 96);
        } else if (tid < 240) {
            if (tau >= 4 && tau <= 515) gemm_sec<16, 2, 2>(wr, bs, tid - 192, hbuf[4], gate, 528);
        } else if (tid < 288) {
            if (tau >= 1 && tau <= 512) gemm_sec< 8, 4, 2>(wr, bs, tid - 240, hbuf[0], gate, 192);
        } else if (tid < 312) {
            if (tau >= 1 && tau <= 512) gemm_sec< 8, 2, 2>(wr, bs, tid - 288, hbuf[1], gate, 240);
        } else if (tid < 336) {
            if (tau >= 3 && tau <= 514) gemm_sec< 8, 2, 2>(wr, bs, tid - 312, hbuf[3], gate, 384);
        } else if (tid < 384) {
            if (tau >= 4 && tau <= 515) gemm_sec< 8, 2, 2>(wr, bs, tid - 336, hbuf[3], gate, 432);
        } else if (tid < 448) {
            if (tau >= 5)               out_sec< 8, 4, 2>(wr, bs, tid - 384, hbuf[4],
                                            out + ((size_t)b0 * T_STEPS + (tau - 5)) * 64);
        } else if (tid < 460) {
            if (tau >= 2 && tau <= 513) gemm_sec< 8, 2, 2>(wr, bs, tid - 448, hbuf[1], gate, 288);
        } else if (tid < 466) {
            if (tau >= 2 && tau <= 513) gemm_sec< 8, 1, 0>(wr, bs, tid - 460, hbuf[2], gate, 312);
        } else if (tid < 478) {
            if (tau >= 3 && tau <= 514) gemm_sec< 8, 1, 0>(wr, bs, tid - 466, hbuf[2], gate, 336);
        } else if (tid >= 480) {
            if (tau + 1 < T_STEPS) {    // prefetch x(tau+1) into registers
                const int e = tid - 480, b = e >> 4, d0 = (e & 15) << 2;
                xr0 = *(const float4*)&X[((size_t)(b0 + b)     * T_STEPS + (tau + 1)) * D_IN + d0];
                xr1 = *(const float4*)&X[((size_t)(b0 + b + 2) * T_STEPS + (tau + 1)) * D_IN + d0];
            }
        }
        __syncthreads();
        // ================= U phase: all layer updates concurrent =================
        if (tid < 128) {
            if (tau < 512)              upd(32, hbuf[0], tid,       gate, 0,   96);
        } else if (tid < 192) {
            if (tau >= 1 && tau <= 512) upd(16, hbuf[1], tid - 128, gate, 192, 240);
        } else if (tid < 224) {
            if (tau >= 2 && tau <= 513) upd(8,  hbuf[2], tid - 192, gate, 288, 312);
        } else if (tid < 288) {
            if (tau >= 3 && tau <= 514) upd(16, hbuf[3], tid - 224, gate, 336, 384);
        } else if (tid < 416) {
            if (tau >= 4 && tau <= 515) upd(32, hbuf[4], tid - 288, gate, 432, 528);
        } else if (tid >= 480) {
            if (tau + 1 < T_STEPS) {    // commit x(tau+1) to LDS
                const int e = tid - 480, b = e >> 4, d0 = (e & 15) << 2;
                inv0[(d0 + 0) * BC + b] = xr0.x; inv0[(d0 + 1) * BC + b] = xr0.y;
                inv0[(d0 + 2) * BC + b] = xr0.z; inv0[(d0 + 3) * BC + b] = xr0.w;
                inv0[(d0 + 0) * BC + b + 2] = xr1.x; inv0[(d0 + 1) * BC + b + 2] = xr1.y;
                inv0[(d0 + 2) * BC + b + 2] = xr1.z; inv0[(d0 + 3) * BC + b + 2] = xr1.w;
            }
        }
        __syncthreads();
    }
}

extern "C" void kernel_launch(void* const* d_in, const int* in_sizes, int n_in,
                              void* d_out, int out_size, void* d_ws, size_t ws_size,
                              hipStream_t stream)
{
    const float* X = (const float*)d_in[0];
    const float* wih[5]; const float* whh[5]; const float* bih[5]; const float* bhh[5];
    for (int l = 0; l < 5; ++l) {
        wih[l] = (const float*)d_in[1 + 4 * l];
        whh[l] = (const float*)d_in[2 + 4 * l];
        bih[l] = (const float*)d_in[3 + 4 * l];
        bhh[l] = (const float*)d_in[4 + 4 * l];
    }
    const float* wout = (const float*)d_in[21];
    const float* bout = (const float*)d_in[22];

    gru_kernel<<<1024 / BC, BLOCK, 0, stream>>>(
        X,
        wih[0], whh[0], bih[0], bhh[0],
        wih[1], whh[1], bih[1], bhh[1],
        wih[2], whh[2], bih[2], bhh[2],
        wih[3], whh[3], bih[3], bhh[3],
        wih[4], whh[4], bih[4], bhh[4],
        wout, bout,
        (float*)d_out);
}

// Round 5
// 1108.734 us; speedup vs baseline: 1.8302x; 1.6672x over previous
//
#include <hip/hip_runtime.h>

#define T_STEPS 512
#define BC      4       // batch columns per block
#define BLOCK   512
#define GATEB   896     // gate region base (float index into sm)

// ---------------------------------------------------------------------------
// Layer-skewed pipeline, balanced one-body-per-wave edition (BLOCK=512).
//
// R2-R4 post-mortem: all three container failures were BLOCK=1024 variants;
// R0/R1 (BLOCK=512) ran. Reverting to the proven launch shape while keeping
// the rebalance theory: R0/R1 fit tick_us = 0.37 + 0.00775*maxwave_fmaf,
// so capping the max wave at 192 fmaf (one body per wave) predicts ~1.86us
// ticks -> ~960us total.
//
// Exact-fit partition, 512 threads, 0 idle, every wave ONE gemm body:
//   arm   sections                 NJ  KC(rt)  tid        thr  cost
//   NJ6   ih0                      6   8       0-127      128  192   W0-W1
//         hh0                      6   4       128-191     64  192   W2
//         hh4                      6   4       192-255     64  192   W3
//   NJ4   out-proj                 4   4       256-319     64  128   W4
//         ih1                      4   4       320-367     48  128 \ W5 (one
//         pool: ih4|hh3|hh1|ih2    4   2       368-511    144  128 /  body:
//               |ih3|hh2 (K<=16)                                     same tpl)
//   x-prefetch: tid 448-511 (64 thr x 1 float4), commit in U phase.
//
// KC is RUNTIME per lane; butterfly = three `if (KC>m)` guards with
// compile-time masks (ds_swizzle). Mixed-KC waves still run ONE body since
// the template only depends on NJ. Butterfly groups are KC-aligned and never
// straddle sections (all section starts multiples of their KC).
//
// Zero-padded K: ih3/hh2 (true K=8) are treated as K=16 reading h2 rows
// 8-15, which are zeroed at init and never written (upd writes h<H only).
// load_w zeroes weights for ke >= trueK. Same invariant covers all pool
// sections (h1/h2/h3 rows 16-31 stay 0).
//
// LDS: inv reads ke = k0 + (kk^kci) -> distinct 16B granules per kci; all
// input bases are multiples of 32 floats so granule = ke&7. Gate rows at
// gsw(row)=row^((row>>3)&7) (16B-granule XOR, bijective within sections:
// all bases/lengths multiples of 8).
//
// Gate rows: gi0:0 gh0:96 gi1:192 gh1:240 gi2:288 gh2:312 gi3:336 gh3:384
//            gi4:432 gh4:528  (624 rows x 4 floats)
// sm layout (floats): inv0[256] | hbuf 5x128 @256 | gate 2496 @896 = 3392
// ---------------------------------------------------------------------------

__device__ __forceinline__ int gsw(int row) { return row ^ ((row >> 3) & 7); }

__device__ __forceinline__ float sigmoid_f(float x) {
    return 1.0f / (1.0f + __expf(-x));
}
__device__ __forceinline__ float tanh_f(float x) {
    return 1.0f - 2.0f / (__expf(2.0f * x) + 1.0f);
}

// Weight slice -> registers. COMPILE-TIME loop bounds only (rule #20).
// Kd = true K (also the row stride); ke >= Kd loads 0 (zero-padded K).
template<int NJ>
__device__ __forceinline__ void load_w(float (&wr)[48], float (&bs)[6],
                                       const float* __restrict__ Wp,
                                       const float* __restrict__ bp,
                                       int row0, int Kd, int k0, int cswz)
{
#pragma unroll
    for (int j = 0; j < NJ; ++j) {
        bs[j] = bp[row0 + j];
#pragma unroll
        for (int kk = 0; kk < 8; ++kk) {
            const int ke = k0 + (kk ^ cswz);
            wr[j * 8 + kk] = (ke < Kd) ? Wp[(row0 + j) * Kd + ke] : 0.0f;
        }
    }
}

// Gate-GEMM: NJ compile-time, KC runtime (butterfly via guarded fixed masks).
template<int NJ>
__device__ __forceinline__ void gemm_g(const float (&wr)[48], const float (&bs)[6],
                                       int kci, int cswz, int k0, int KC,
                                       float* __restrict__ sm, int inb,
                                       const int (&gwa)[6])
{
    float acc[NJ][4];
#pragma unroll
    for (int j = 0; j < NJ; ++j) {
        const float bj = (kci == 0) ? bs[j] : 0.0f;
#pragma unroll
        for (int b = 0; b < 4; ++b) acc[j][b] = bj;
    }
#pragma unroll
    for (int kk = 0; kk < 8; ++kk) {
        const int ke = k0 + (kk ^ cswz);
        const float4 v = *(const float4*)&sm[inb + ke * 4];
#pragma unroll
        for (int j = 0; j < NJ; ++j) {
            const float w = wr[j * 8 + kk];
            acc[j][0] = fmaf(w, v.x, acc[j][0]);
            acc[j][1] = fmaf(w, v.y, acc[j][1]);
            acc[j][2] = fmaf(w, v.z, acc[j][2]);
            acc[j][3] = fmaf(w, v.w, acc[j][3]);
        }
    }
    // butterfly with compile-time masks; guards diverge but partners of any
    // active lane share its KC (groups are KC-aligned within one section).
    if (KC > 1) {
#pragma unroll
        for (int j = 0; j < NJ; ++j) {
            acc[j][0] += __shfl_xor(acc[j][0], 1, 64);
            acc[j][1] += __shfl_xor(acc[j][1], 1, 64);
            acc[j][2] += __shfl_xor(acc[j][2], 1, 64);
            acc[j][3] += __shfl_xor(acc[j][3], 1, 64);
        }
    }
    if (KC > 2) {
#pragma unroll
        for (int j = 0; j < NJ; ++j) {
            acc[j][0] += __shfl_xor(acc[j][0], 2, 64);
            acc[j][1] += __shfl_xor(acc[j][1], 2, 64);
            acc[j][2] += __shfl_xor(acc[j][2], 2, 64);
            acc[j][3] += __shfl_xor(acc[j][3], 2, 64);
        }
    }
    if (KC > 4) {
#pragma unroll
        for (int j = 0; j < NJ; ++j) {
            acc[j][0] += __shfl_xor(acc[j][0], 4, 64);
            acc[j][1] += __shfl_xor(acc[j][1], 4, 64);
            acc[j][2] += __shfl_xor(acc[j][2], 4, 64);
            acc[j][3] += __shfl_xor(acc[j][3], 4, 64);
        }
    }
    if (kci == 0) {
#pragma unroll
        for (int j = 0; j < NJ; ++j) {
            float4 o = {acc[j][0], acc[j][1], acc[j][2], acc[j][3]};
            *(float4*)&sm[gwa[j]] = o;
        }
    }
}

// Output projection: NJ=4, KC=4 fixed, writes global.
__device__ __forceinline__ void out_g(const float (&wr)[48], const float (&bs)[6],
                                      int kci, int cswz, int k0,
                                      const float* __restrict__ sm, int inb, int row0,
                                      float* __restrict__ outp)
{
    float acc[4][4];
#pragma unroll
    for (int j = 0; j < 4; ++j) {
        const float bj = (kci == 0) ? bs[j] : 0.0f;
#pragma unroll
        for (int b = 0; b < 4; ++b) acc[j][b] = bj;
    }
#pragma unroll
    for (int kk = 0; kk < 8; ++kk) {
        const int ke = k0 + (kk ^ cswz);
        const float4 v = *(const float4*)&sm[inb + ke * 4];
#pragma unroll
        for (int j = 0; j < 4; ++j) {
            const float w = wr[j * 8 + kk];
            acc[j][0] = fmaf(w, v.x, acc[j][0]);
            acc[j][1] = fmaf(w, v.y, acc[j][1]);
            acc[j][2] = fmaf(w, v.z, acc[j][2]);
            acc[j][3] = fmaf(w, v.w, acc[j][3]);
        }
    }
#pragma unroll
    for (int m = 1; m < 4; m <<= 1)
#pragma unroll
        for (int j = 0; j < 4; ++j) {
            acc[j][0] += __shfl_xor(acc[j][0], m, 64);
            acc[j][1] += __shfl_xor(acc[j][1], m, 64);
            acc[j][2] += __shfl_xor(acc[j][2], m, 64);
            acc[j][3] += __shfl_xor(acc[j][3], m, 64);
        }
    if (kci == 0) {
#pragma unroll
        for (int b = 0; b < 4; ++b) {
            float4 o = {acc[0][b], acc[1][b], acc[2][b], acc[3][b]};
            *(float4*)&outp[(size_t)b * (T_STEPS * 64) + row0] = o;
        }
    }
}

__global__ __launch_bounds__(BLOCK, 2)
void gru_kernel(const float* __restrict__ X,
                const float* wih0, const float* whh0, const float* bih0, const float* bhh0,
                const float* wih1, const float* whh1, const float* bih1, const float* bhh1,
                const float* wih2, const float* whh2, const float* bih2, const float* bhh2,
                const float* wih3, const float* whh3, const float* bih3, const float* bhh3,
                const float* wih4, const float* whh4, const float* bih4, const float* bhh4,
                const float* wout, const float* bout,
                float* __restrict__ out)
{
    __shared__ __align__(16) float sm[3392];

    const int tid = threadIdx.x;
    const int b0  = blockIdx.x * BC;

    float wr[48];
    float bs[6];

    // ---- per-lane G-phase parameters ----
    int kci = 0, KC = 1, inb = 0, growA = 0, lo = 1, hi = 0, row0 = 0, Kd = 8;
    const float* Wp = nullptr; const float* bp = nullptr;

    if (tid < 128) {                      // ih0: NJ6, KC8, K=64, input x
        kci = tid & 7; KC = 8; row0 = (tid >> 3) * 6; Kd = 64;
        inb = 0; growA = 0 + row0; lo = 0; hi = 511; Wp = wih0; bp = bih0;
    } else if (tid < 192) {               // hh0: NJ6, KC4, K=32, input h0
        const int l = tid - 128; kci = l & 3; KC = 4; row0 = (l >> 2) * 6; Kd = 32;
        inb = 256; growA = 96 + row0; lo = 0; hi = 511; Wp = whh0; bp = bhh0;
    } else if (tid < 256) {               // hh4: NJ6, KC4, K=32, input h4
        const int l = tid - 192; kci = l & 3; KC = 4; row0 = (l >> 2) * 6; Kd = 32;
        inb = 768; growA = 528 + row0; lo = 4; hi = 515; Wp = whh4; bp = bhh4;
    } else if (tid < 320) {               // out-proj: NJ4, KC4, K=32, input h4
        const int l = tid - 256; kci = l & 3; KC = 4; row0 = (l >> 2) * 4; Kd = 32;
        inb = 768; lo = 5; hi = 516; Wp = wout; bp = bout;
    } else if (tid < 368) {               // ih1: NJ4, KC4, K=32, input h0
        const int l = tid - 320; kci = l & 3; KC = 4; row0 = (l >> 2) * 4; Kd = 32;
        inb = 256; growA = 192 + row0; lo = 1; hi = 512; Wp = wih1; bp = bih1;
    } else {                              // pool: NJ4, KC2, K<=16 zero-padded
        const int l = tid - 368; kci = l & 1; KC = 2;
        const int rg = l >> 1;            // rg in [0,72), 4 rows each
        if (rg < 24)      { row0 = rg * 4;        Wp = wih4; bp = bih4; Kd = 16;
                            inb = 640; growA = 432 + row0; lo = 4; hi = 515; }
        else if (rg < 36) { row0 = (rg - 24) * 4; Wp = whh3; bp = bhh3; Kd = 16;
                            inb = 640; growA = 384 + row0; lo = 3; hi = 514; }
        else if (rg < 48) { row0 = (rg - 36) * 4; Wp = whh1; bp = bhh1; Kd = 16;
                            inb = 384; growA = 240 + row0; lo = 1; hi = 512; }
        else if (rg < 54) { row0 = (rg - 48) * 4; Wp = wih2; bp = bih2; Kd = 16;
                            inb = 384; growA = 288 + row0; lo = 2; hi = 513; }
        else if (rg < 66) { row0 = (rg - 54) * 4; Wp = wih3; bp = bih3; Kd = 8;
                            inb = 512; growA = 336 + row0; lo = 3; hi = 514; }
        else              { row0 = (rg - 66) * 4; Wp = whh2; bp = bhh2; Kd = 8;
                            inb = 512; growA = 312 + row0; lo = 2; hi = 513; }
    }
    const int cswz = kci;
    const int k0   = kci * 8;

    // ---- weight slices into registers (compile-time-indexed stores only) ----
    if (tid < 256) load_w<6>(wr, bs, Wp, bp, row0, Kd, k0, cswz);
    else           load_w<4>(wr, bs, Wp, bp, row0, Kd, k0, cswz);

    // ---- precomputed swizzled gate-write addresses ----
    int gwa[6];
#pragma unroll
    for (int j = 0; j < 6; ++j) gwa[j] = GATEB + gsw(growA + j) * 4;

    // ---- per-lane U-phase parameters ----
    int a_ir = 0, a_iz = 0, a_in = 0, a_hr = 0, a_hz = 0, a_hn = 0, hoff = 0;
    int ulo = 1, uhi = 0;
    if (tid < 416) {
        int l, h; const int b = tid & 3;
        if      (tid < 128) { l = 0; h = tid >> 2; }
        else if (tid < 192) { l = 1; h = (tid - 128) >> 2; }
        else if (tid < 224) { l = 2; h = (tid - 192) >> 2; }
        else if (tid < 288) { l = 3; h = (tid - 224) >> 2; }
        else                { l = 4; h = (tid - 288) >> 2; }
        int giB, ghB, H;
        if      (l == 0) { giB = 0;   ghB = 96;  H = 32; }
        else if (l == 1) { giB = 192; ghB = 240; H = 16; }
        else if (l == 2) { giB = 288; ghB = 312; H = 8;  }
        else if (l == 3) { giB = 336; ghB = 384; H = 16; }
        else             { giB = 432; ghB = 528; H = 32; }
        a_ir = GATEB + gsw(giB + h) * 4 + b;
        a_iz = GATEB + gsw(giB + H + h) * 4 + b;
        a_in = GATEB + gsw(giB + 2 * H + h) * 4 + b;
        a_hr = GATEB + gsw(ghB + h) * 4 + b;
        a_hz = GATEB + gsw(ghB + H + h) * 4 + b;
        a_hn = GATEB + gsw(ghB + 2 * H + h) * 4 + b;
        hoff = 256 + l * 128 + h * 4 + b;
        ulo = l; uhi = 511 + l;
    }

    // ---- init: zero h states (incl. padding rows), stage x(0) ----
    for (int i = 256 + tid; i < GATEB; i += BLOCK) sm[i] = 0.0f;
    if (tid >= 448) {
        const int e = tid - 448, xb = e & 3, xd0 = (e >> 2) << 2;
        const float4 v = *(const float4*)&X[(size_t)(b0 + xb) * (T_STEPS * 64) + xd0];
        sm[(xd0 + 0) * 4 + xb] = v.x; sm[(xd0 + 1) * 4 + xb] = v.y;
        sm[(xd0 + 2) * 4 + xb] = v.z; sm[(xd0 + 3) * 4 + xb] = v.w;
    }
    __syncthreads();

    float4 xr = {0.f, 0.f, 0.f, 0.f};

    for (int tau = 0; tau < T_STEPS + 5; ++tau) {
        const bool act = (tau >= lo) && (tau <= hi);
        // ================= G phase =================
        if (tid < 256) {
            if (act) gemm_g<6>(wr, bs, kci, cswz, k0, KC, sm, inb, gwa);
        } else if (tid < 320) {
            if (act) out_g(wr, bs, kci, cswz, k0, sm, inb, row0,
                           out + ((size_t)b0 * T_STEPS + (tau - 5)) * 64);
        } else {
            if (tid >= 448 && tau + 1 < T_STEPS) {   // x(tau+1) prefetch
                const int e = tid - 448, xb = e & 3, xd0 = (e >> 2) << 2;
                xr = *(const float4*)&X[((size_t)(b0 + xb) * T_STEPS + (tau + 1)) * 64 + xd0];
            }
            if (act) gemm_g<4>(wr, bs, kci, cswz, k0, KC, sm, inb, gwa);
        }
        __syncthreads();
        // ================= U phase =================
        if (tid < 416 && tau >= ulo && tau <= uhi) {
            const float r = sigmoid_f(sm[a_ir] + sm[a_hr]);
            const float z = sigmoid_f(sm[a_iz] + sm[a_hz]);
            const float n = tanh_f(sm[a_in] + r * sm[a_hn]);
            sm[hoff] = (1.0f - z) * n + z * sm[hoff];
        }
        if (tid >= 448 && tau + 1 < T_STEPS) {       // commit x(tau+1)
            const int e = tid - 448, xb = e & 3, xd0 = (e >> 2) << 2;
            sm[(xd0 + 0) * 4 + xb] = xr.x; sm[(xd0 + 1) * 4 + xb] = xr.y;
            sm[(xd0 + 2) * 4 + xb] = xr.z; sm[(xd0 + 3) * 4 + xb] = xr.w;
        }
        __syncthreads();
    }
}

extern "C" void kernel_launch(void* const* d_in, const int* in_sizes, int n_in,
                              void* d_out, int out_size, void* d_ws, size_t ws_size,
                              hipStream_t stream)
{
    const float* X = (const float*)d_in[0];
    const float* wih[5]; const float* whh[5]; const float* bih[5]; const float* bhh[5];
    for (int l = 0; l < 5; ++l) {
        wih[l] = (const float*)d_in[1 + 4 * l];
        whh[l] = (const float*)d_in[2 + 4 * l];
        bih[l] = (const float*)d_in[3 + 4 * l];
        bhh[l] = (const float*)d_in[4 + 4 * l];
    }
    const float* wout = (const float*)d_in[21];
    const float* bout = (const float*)d_in[22];

    gru_kernel<<<1024 / BC, BLOCK, 0, stream>>>(
        X,
        wih[0], whh[0], bih[0], bhh[0],
        wih[1], whh[1], bih[1], bhh[1],
        wih[2], whh[2], bih[2], bhh[2],
        wih[3], whh[3], bih[3], bhh[3],
        wih[4], whh[4], bih[4], bhh[4],
        wout, bout,
        (float*)d_out);
}